// Round 12
// baseline (480.045 us; speedup 1.0000x reference)
//
#include <hip/hip_runtime.h>
#include <hip/hip_cooperative_groups.h>
#include <math.h>

namespace cg = cooperative_groups;

#define N_N 20000
#define N_E 160000
#define KA 2112   // A cols: 2048 (P) + 32 (xsum for b2) + 32 (x*cnt for root_w)
#define NKB 66

typedef __attribute__((ext_vector_type(8))) short bfrag;
typedef __attribute__((ext_vector_type(4))) float facc;

__device__ __forceinline__ unsigned short f2bf(float f) {
  union { float f; unsigned u; } v; v.f = f;
  unsigned u = v.u;
  return (unsigned short)((u + 0x7FFF + ((u >> 16) & 1)) >> 16);
}
__device__ __forceinline__ unsigned pk2(float a, float b) {
  return (unsigned)f2bf(a) | ((unsigned)f2bf(b) << 16);
}
__device__ __forceinline__ float bflo(unsigned u) {
  union { unsigned u; float f; } v; v.u = u << 16; return v.f;
}
__device__ __forceinline__ float bfhi(unsigned u) {
  union { unsigned u; float f; } v; v.u = u & 0xffff0000u; return v.f;
}

// ============ ONE cooperative preprocessing kernel ============
// phases: A pack+zero | B hist | C1/C2/C3 scan | D scatter | E mlp1
__global__ __launch_bounds__(256, 2) void k_pre(
    const float* __restrict__ ea, const float* __restrict__ w1,
    const float* __restrict__ b1, const int* __restrict__ eidx,
    const float* __restrict__ w2, const float* __restrict__ b2f,
    const float* __restrict__ rootw, const float* __restrict__ inw,
    unsigned short* __restrict__ Bp, unsigned short* __restrict__ B2p,
    int* __restrict__ cursor, int* __restrict__ starts,
    int* __restrict__ elist, int* __restrict__ srcl,
    unsigned short* __restrict__ hes, int* __restrict__ chunkAux) {
  cg::grid_group grid = cg::this_grid();
  __shared__ int sc[256];
  int t = threadIdx.x, b = blockIdx.x;
  int gtid = b * 256 + t;
  const int GT = 512 * 256;
  const int nchunks = (N_N + 255) / 256;   // 79

  // ---- phase A: pack Bp/B2p fragment layouts + zero cursor ----
  for (int idx = gtid; idx < 135168 + 12288; idx += GT) {
    if (idx < 135168) {
      int i = idx & 7, l = (idx >> 3) & 63, cbkb = idx >> 9;
      int cb = cbkb & 3, kb = cbkb >> 2;
      int r = kb * 32 + ((l >> 4) << 3) + i;
      int c = (cb << 4) + (l & 15);
      float v;
      if (r < 2048) { int d = r >> 6, k = r & 63; v = w2[((d << 6) + c) * 64 + k]; }
      else if (r < 2080) v = b2f[((r - 2048) << 6) + c];
      else v = rootw[((r - 2080) << 6) + c];
      Bp[idx] = f2bf(v);
    } else {
      int k2 = idx - 135168;
      int i = k2 & 7, l = (k2 >> 3) & 63, cbkb = k2 >> 9;
      int cb = cbkb % 12, kb = cbkb / 12;
      int r = kb * 32 + ((l >> 4) << 3) + i;
      int c = (cb << 4) + (l & 15);
      B2p[k2] = f2bf(inw[c * 64 + r]);
    }
  }
  for (int i = gtid; i < N_N; i += GT) cursor[i] = 0;
  grid.sync();

  // ---- phase B: histogram by dst ----
  for (int e = gtid; e < N_E; e += GT) atomicAdd(&cursor[eidx[N_E + e]], 1);
  grid.sync();

  // ---- phase C1: block-local exclusive scan over 256-node chunks ----
  if (b < nchunks) {
    int i = b * 256 + t;
    int v = (i < N_N) ? cursor[i] : 0;
    sc[t] = v;
    __syncthreads();
    for (int off = 1; off < 256; off <<= 1) {
      int u = (t >= off) ? sc[t - off] : 0;
      __syncthreads();
      sc[t] += u;
      __syncthreads();
    }
    if (i < N_N) starts[i] = sc[t] - v;
    if (t == 255) chunkAux[b] = sc[255];
  }
  grid.sync();

  // ---- phase C2: scan the chunk totals (block 0) ----
  if (b == 0) {
    int v = (t < nchunks) ? chunkAux[t] : 0;
    sc[t] = v;
    __syncthreads();
    for (int off = 1; off < 256; off <<= 1) {
      int u = (t >= off) ? sc[t - off] : 0;
      __syncthreads();
      sc[t] += u;
      __syncthreads();
    }
    if (t < nchunks) chunkAux[t] = sc[t] - v;
  }
  grid.sync();

  // ---- phase C3: add chunk offsets; seed scatter cursor ----
  if (b < nchunks) {
    int i = b * 256 + t;
    if (i < N_N) {
      int s = starts[i] + chunkAux[b];
      starts[i] = s;
      cursor[i] = s;
    }
  }
  if (gtid == 0) starts[N_N] = N_E;
  grid.sync();

  // ---- phase D: scatter edge->slot ----
  for (int e = gtid; e < N_E; e += GT) {
    int dn = eidx[N_E + e];
    int pos = atomicAdd(&cursor[dn], 1);
    elist[pos] = e;
    srcl[pos] = eidx[e];
  }
  grid.sync();

  // ---- phase E: edge MLP layer 1, slot-ordered (coalesced hes writes) ----
  {
    int w = t >> 6, j = t & 63;
    float wr[16];
#pragma unroll
    for (int i = 0; i < 16; ++i) wr[i] = w1[j * 16 + i];
    float bj = b1[j];
    int wid = b * 4 + w;                      // 0..2047
#pragma unroll 1
    for (int p0 = wid * 8; p0 < N_E; p0 += 2048 * 8) {
#pragma unroll
      for (int q = 0; q < 8; ++q) {
        int p = p0 + q;
        int e = elist[p];
        const float* a = ea + (size_t)e * 16;
        float s = bj;
#pragma unroll
        for (int i = 0; i < 16; ++i) s += a[i] * wr[i];
        hes[(size_t)p * 64 + j] = f2bf(fmaxf(s, 0.f));
      }
    }
  }
}

// ---------------- FUSED: P-build (LDS) + MFMA GEMM (M=8) + mean/bias/relu + QKV ----------
#define FMA8(hv, base, xv) \
  acc[base + 0] += xv * bflo(hv.x); acc[base + 1] += xv * bfhi(hv.x); \
  acc[base + 2] += xv * bflo(hv.y); acc[base + 3] += xv * bfhi(hv.y); \
  acc[base + 4] += xv * bflo(hv.z); acc[base + 5] += xv * bfhi(hv.z); \
  acc[base + 6] += xv * bflo(hv.w); acc[base + 7] += xv * bfhi(hv.w);

__global__ __launch_bounds__(256, 4) void k_fused(const float* __restrict__ x,
    const unsigned short* __restrict__ hes, const int* __restrict__ starts,
    const int* __restrict__ srcl,
    const unsigned short* __restrict__ Bp, const unsigned short* __restrict__ B2p,
    const float* __restrict__ convb, const float* __restrict__ inb,
    float* __restrict__ Qb, float* __restrict__ Kb, float* __restrict__ Vb) {
  __shared__ unsigned short Ps[8 * KA];      // 33,792 B
  __shared__ unsigned short xhT[8 * 68];     //  1,088 B
  int t = threadIdx.x, w = t >> 6, l = t & 63;
  int n0 = blockIdx.x * 8;
  int d0 = l >> 3, hc = (l & 7) * 8, l31 = l & 31;
#pragma unroll 1
  for (int i4 = 0; i4 < 2; ++i4) {
    int m = w * 2 + i4;
    int n = n0 + m;
    int s0 = starts[n], s1 = starts[n + 1];
    float acc[32];
#pragma unroll
    for (int z = 0; z < 32; ++z) acc[z] = 0.f;
    float xs = 0.f;
#pragma unroll 1
    for (int c0 = s0; c0 < s1; c0 += 64) {
      int srv = 0;
      if (c0 + l < s1) srv = srcl[c0 + l];
      int cc = s1 - c0; if (cc > 64) cc = 64;
#pragma unroll 1
      for (int i = 0; i < cc; i += 4) {
        uint4 h0 = {0,0,0,0}, h1 = {0,0,0,0}, h2 = {0,0,0,0}, h3 = {0,0,0,0};
        float xv0 = 0.f, xv1 = 0.f, xv2 = 0.f, xv3 = 0.f;
        int sr0 = __shfl(srv, i);
        int sr1 = __shfl(srv, i + 1);
        int sr2 = __shfl(srv, i + 2);
        int sr3 = __shfl(srv, i + 3);
        const unsigned short* hp = hes + (size_t)(c0 + i) * 64 + hc;
        h0 = *(const uint4*)hp;
        xv0 = x[(size_t)sr0 * 32 + l31];
        if (i + 1 < cc) { h1 = *(const uint4*)(hp + 64);  xv1 = x[(size_t)sr1 * 32 + l31]; }
        if (i + 2 < cc) { h2 = *(const uint4*)(hp + 128); xv2 = x[(size_t)sr2 * 32 + l31]; }
        if (i + 3 < cc) { h3 = *(const uint4*)(hp + 192); xv3 = x[(size_t)sr3 * 32 + l31]; }
        float a0 = __shfl(xv0, d0),      a1 = __shfl(xv0, d0 + 8);
        float a2 = __shfl(xv0, d0 + 16), a3 = __shfl(xv0, d0 + 24);
        FMA8(h0, 0, a0) FMA8(h0, 8, a1) FMA8(h0, 16, a2) FMA8(h0, 24, a3)
        float b0 = __shfl(xv1, d0),      b1 = __shfl(xv1, d0 + 8);
        float b2 = __shfl(xv1, d0 + 16), b3 = __shfl(xv1, d0 + 24);
        FMA8(h1, 0, b0) FMA8(h1, 8, b1) FMA8(h1, 16, b2) FMA8(h1, 24, b3)
        float c0f = __shfl(xv2, d0),      c1f = __shfl(xv2, d0 + 8);
        float c2f = __shfl(xv2, d0 + 16), c3f = __shfl(xv2, d0 + 24);
        FMA8(h2, 0, c0f) FMA8(h2, 8, c1f) FMA8(h2, 16, c2f) FMA8(h2, 24, c3f)
        float e0 = __shfl(xv3, d0),      e1 = __shfl(xv3, d0 + 8);
        float e2 = __shfl(xv3, d0 + 16), e3 = __shfl(xv3, d0 + 24);
        FMA8(h3, 0, e0) FMA8(h3, 8, e1) FMA8(h3, 16, e2) FMA8(h3, 24, e3)
        xs += xv0 + xv1 + xv2 + xv3;
      }
    }
    int s = m;
#pragma unroll
    for (int q = 0; q < 4; ++q) {
      int scr = (l + 64 * q) ^ s;
      uint4 o;
      o.x = pk2(acc[q * 8 + 0], acc[q * 8 + 1]);
      o.y = pk2(acc[q * 8 + 2], acc[q * 8 + 3]);
      o.z = pk2(acc[q * 8 + 4], acc[q * 8 + 5]);
      o.w = pk2(acc[q * 8 + 6], acc[q * 8 + 7]);
      *(uint4*)(Ps + m * KA + scr * 8) = o;
    }
    if (l < 32) {
      int cnt = s1 - s0; if (cnt < 1) cnt = 1;
      int c1 = (256 + (l >> 3)) ^ s, c2 = (260 + (l >> 3)) ^ s;
      Ps[m * KA + c1 * 8 + (l & 7)] = f2bf(xs);
      Ps[m * KA + c2 * 8 + (l & 7)] = f2bf(x[(size_t)n * 32 + l] * (float)cnt);
    }
  }
  __syncthreads();
  int col = l & 15, sub = l >> 4;
  int arow = col & 7;
  const bfrag* Bb = (const bfrag*)Bp + w * 64 + l;
  facc ac = {0.f, 0.f, 0.f, 0.f};
#pragma unroll 4
  for (int kb = 0; kb < NKB; ++kb) {
    int scr = ((kb << 2) + sub) ^ arow;
    bfrag af = *(const bfrag*)(Ps + arow * KA + scr * 8);
    ac = __builtin_amdgcn_mfma_f32_16x16x32_bf16(af, Bb[kb * 256], ac, 0, 0, 0);
  }
  float cv = convb[w * 16 + col];
#pragma unroll
  for (int j = 0; j < 4; ++j) {
    int m = sub * 4 + j;
    if (m < 8) {
      int n = n0 + m;
      int cnt = starts[n + 1] - starts[n]; if (cnt < 1) cnt = 1;
      float inv = 1.f / (float)cnt;
      xhT[m * 68 + w * 16 + col] = f2bf(fmaxf(ac[j] * inv + cv, 0.f));
    }
  }
  __syncthreads();
  bfrag af0 = *(const bfrag*)&xhT[(col & 7) * 68 + sub * 8];
  bfrag af1 = *(const bfrag*)&xhT[(col & 7) * 68 + 32 + sub * 8];
  const bfrag* B2b = (const bfrag*)B2p + l;
#pragma unroll
  for (int c3 = 0; c3 < 3; ++c3) {
    int cb = w * 3 + c3;
    facc qa = {0.f, 0.f, 0.f, 0.f};
    qa = __builtin_amdgcn_mfma_f32_16x16x32_bf16(af0, B2b[cb * 64], qa, 0, 0, 0);
    qa = __builtin_amdgcn_mfma_f32_16x16x32_bf16(af1, B2b[(12 + cb) * 64], qa, 0, 0, 0);
#pragma unroll
    for (int j = 0; j < 4; ++j) {
      int m = sub * 4 + j;
      if (m < 8) {
        int n = n0 + m;
        int g = n / 200, p = n - g * 200;
        int c = cb * 16 + col;
        float v = qa[j] + inb[c];
        int part = c >> 6, rem = c & 63, hh = rem >> 4, dd = rem & 15;
        float* dst = (part == 0) ? Qb : (part == 1 ? Kb : Vb);
        dst[(((size_t)g * 4 + hh) * 200 + p) * 16 + dd] = v;
      }
    }
  }
}

// ---------------- MFMA flash attention: two blocks per (graph, head) ----------------
__global__ __launch_bounds__(256) void k_attn(const float* __restrict__ Qb,
    const float* __restrict__ Kb, const float* __restrict__ Vb,
    float* __restrict__ ctx) {
  __shared__ unsigned short Ks[224 * 24];
  __shared__ unsigned short Vt[16 * 232];
  __shared__ unsigned short Pl[4][16 * 40];
  int t = threadIdx.x;
  int gh = blockIdx.x >> 1, half = blockIdx.x & 1;
  size_t base = (size_t)gh * 3200;
  for (int idx = t; idx < 224 * 16; idx += 256) {
    int row = idx >> 4, d = idx & 15;
    float kv = (row < 200) ? Kb[base + idx] : 0.f;
    float vv = (row < 200) ? Vb[base + idx] : 0.f;
    Ks[row * 24 + d] = f2bf(kv);
    Vt[d * 232 + row] = f2bf(vv);
  }
  __syncthreads();
  int w = t >> 6, l = t & 63;
  int sub = l >> 4, col = l & 15;
  int qlo = half * 7, qhi = half ? 13 : 7;
  for (int qt = qlo + w; qt < qhi; qt += 4) {
    bfrag qf = {0, 0, 0, 0, 0, 0, 0, 0};
    int q = qt * 16 + col;
    if (sub < 2 && q < 200) {
      const float* qp = Qb + base + q * 16 + sub * 8;
      float4 qa = *(const float4*)qp;
      float4 qb = *(const float4*)(qp + 4);
      qf[0] = (short)f2bf(qa.x); qf[1] = (short)f2bf(qa.y);
      qf[2] = (short)f2bf(qa.z); qf[3] = (short)f2bf(qa.w);
      qf[4] = (short)f2bf(qb.x); qf[5] = (short)f2bf(qb.y);
      qf[6] = (short)f2bf(qb.z); qf[7] = (short)f2bf(qb.w);
    }
    facc o = {0.f, 0.f, 0.f, 0.f};
    float srow0 = 0.f, srow1 = 0.f, srow2 = 0.f, srow3 = 0.f;
    for (int kt2 = 0; kt2 < 7; ++kt2) {
      int kt0 = kt2 * 2, kt1 = kt0 + 1;
      bfrag kf0 = {0, 0, 0, 0, 0, 0, 0, 0};
      bfrag kf1 = {0, 0, 0, 0, 0, 0, 0, 0};
      if (sub < 2) {
        kf0 = *(const bfrag*)&Ks[(kt0 * 16 + col) * 24 + sub * 8];
        kf1 = *(const bfrag*)&Ks[(kt1 * 16 + col) * 24 + sub * 8];
      }
      facc z = {0.f, 0.f, 0.f, 0.f};
      facc s0 = __builtin_amdgcn_mfma_f32_16x16x32_bf16(qf, kf0, z, 0, 0, 0);
      facc s1 = __builtin_amdgcn_mfma_f32_16x16x32_bf16(qf, kf1, z, 0, 0, 0);
      bool ok0 = (kt0 * 16 + col) < 200;
      bool ok1 = (kt1 * 16 + col) < 200;
#pragma unroll
      for (int j = 0; j < 4; ++j) {
        float e0 = ok0 ? __expf(s0[j] * 0.25f) : 0.f;
        float e1 = ok1 ? __expf(s1[j] * 0.25f) : 0.f;
        if (j == 0) { srow0 += e0 + e1; } else if (j == 1) { srow1 += e0 + e1; }
        else if (j == 2) { srow2 += e0 + e1; } else { srow3 += e0 + e1; }
        int qr = (sub << 2) + j;
        Pl[w][qr * 40 + col] = f2bf(e0);
        Pl[w][qr * 40 + 16 + col] = f2bf(e1);
      }
      bfrag pf = *(const bfrag*)&Pl[w][col * 40 + sub * 8];
      bfrag vf = *(const bfrag*)&Vt[col * 232 + kt2 * 32 + sub * 8];
      o = __builtin_amdgcn_mfma_f32_16x16x32_bf16(pf, vf, o, 0, 0, 0);
    }
#pragma unroll
    for (int off = 1; off < 16; off <<= 1) {
      srow0 += __shfl_xor(srow0, off);
      srow1 += __shfl_xor(srow1, off);
      srow2 += __shfl_xor(srow2, off);
      srow3 += __shfl_xor(srow3, off);
    }
#pragma unroll
    for (int j = 0; j < 4; ++j) {
      int qq = qt * 16 + (sub << 2) + j;
      float sr = (j == 0) ? srow0 : (j == 1) ? srow1 : (j == 2) ? srow2 : srow3;
      if (qq < 200) ctx[base + qq * 16 + col] = o[j] / sr;
    }
  }
}

// ---------------- pool + MLP head (256 threads: 4-way split pool) ----------------
__global__ __launch_bounds__(256) void k_head(const float* __restrict__ ctx,
    const float* __restrict__ ow, const float* __restrict__ ob,
    const float* __restrict__ w1, const float* __restrict__ b1,
    const float* __restrict__ w2, const float* __restrict__ b2,
    float* __restrict__ out) {
  __shared__ float pool[4][64];
  __shared__ float ms[64], es[64];
  int g = blockIdx.x, t = threadIdx.x;
  int q = t >> 6, c = t & 63;
  int hh = c >> 4, dd = c & 15;
  const float* cb = ctx + (((size_t)g * 4 + hh) * 200) * 16 + dd;
  float s = 0.f;
  for (int p = q; p < 200; p += 4) s += cb[p * 16];
  pool[q][c] = s;
  __syncthreads();
  if (t < 64) {
    float sm = pool[0][t] + pool[1][t] + pool[2][t] + pool[3][t];
    ms[t] = sm * (1.f / 200.f);
  }
  __syncthreads();
  if (t < 64) {
    float e = ob[t];
    for (int j = 0; j < 64; ++j) e += ow[t * 64 + j] * ms[j];
    es[t] = e;
  }
  __syncthreads();
  if (t < 64) {
    float h1 = b1[t];
    for (int j = 0; j < 64; ++j) h1 += w1[t * 64 + j] * es[j];
    h1 = fmaxf(h1, 0.f);
    float pr = h1 * w2[t];
    for (int off = 32; off >= 1; off >>= 1) pr += __shfl_xor(pr, off);
    if (t == 0) out[g] = pr + b2[0];
  }
}

extern "C" void kernel_launch(void* const* d_in, const int* in_sizes, int n_in,
                              void* d_out, int out_size, void* d_ws, size_t ws_size,
                              hipStream_t stream) {
  (void)in_sizes; (void)n_in;
  const float* x      = (const float*)d_in[0];
  const int*   eidx   = (const int*)d_in[1];
  const float* ea     = (const float*)d_in[2];
  const float* en_w1  = (const float*)d_in[4];
  const float* en_b1  = (const float*)d_in[5];
  const float* en_w2  = (const float*)d_in[6];
  const float* en_b2  = (const float*)d_in[7];
  const float* root_w = (const float*)d_in[8];
  const float* conv_b = (const float*)d_in[9];
  const float* in_w   = (const float*)d_in[10];
  const float* in_b   = (const float*)d_in[11];
  const float* out_w  = (const float*)d_in[12];
  const float* out_b  = (const float*)d_in[13];
  const float* l1w    = (const float*)d_in[14];
  const float* l1b    = (const float*)d_in[15];
  const float* l2w    = (const float*)d_in[16];
  const float* l2b    = (const float*)d_in[17];
  float* out = (float*)d_out;

  // ---- workspace layout (bytes) ----
  char* w = (char*)d_ws;
  unsigned short* hes = (unsigned short*)w;            // 20,480,000 (dst-sorted he)
  float* Qb  = (float*)(w + 20480000);
  float* Kb  = (float*)(w + 25600000);
  float* Vb  = (float*)(w + 30720000);
  float* ctx = (float*)(w + 35840000);                 // ends 40,960,000
  char* r3 = w + 40960000;
  unsigned short* Bp  = (unsigned short*)r3;             // 270,336
  unsigned short* B2p = (unsigned short*)(r3 + 270336);  // 24,576
  int* starts = (int*)(r3 + 270336 + 24576);
  int* elist  = starts + (N_N + 4);
  int* srcl   = elist + N_E;
  int* cursor = srcl + N_E;
  int* chunkAux = cursor + N_N;                          // 256 ints
  size_t need = 40960000 + 270336 + 24576
              + (size_t)(N_N + 4) * 4 + 2 * (size_t)N_E * 4 + (size_t)N_N * 4 + 1024;
  if (ws_size < need || out_size < 100) return;

  void* args[] = { (void*)&ea, (void*)&en_w1, (void*)&en_b1, (void*)&eidx,
                   (void*)&en_w2, (void*)&en_b2, (void*)&root_w, (void*)&in_w,
                   (void*)&Bp, (void*)&B2p, (void*)&cursor, (void*)&starts,
                   (void*)&elist, (void*)&srcl, (void*)&hes, (void*)&chunkAux };
  hipLaunchCooperativeKernel((const void*)k_pre, dim3(512), dim3(256), args, 0, stream);
  k_fused<<<2500, 256, 0, stream>>>(x, hes, starts, srcl, Bp, B2p,
                                    conv_b, in_b, Qb, Kb, Vb);
  k_attn<<<800, 256, 0, stream>>>(Qb, Kb, Vb, ctx);
  k_head<<<100, 256, 0, stream>>>(ctx, out_w, out_b, l1w, l1b, l2w, l2b, out);
}

// Round 13
// 297.745 us; speedup vs baseline: 1.6123x; 1.6123x over previous
//
#include <hip/hip_runtime.h>
#include <math.h>

#define N_N 20000
#define N_E 160000
#define KA 2112   // A cols: 2048 (P) + 32 (xsum for b2) + 32 (x*cnt for root_w)
#define NKB 66

typedef __attribute__((ext_vector_type(8))) short bfrag;
typedef __attribute__((ext_vector_type(4))) float facc;

__device__ __forceinline__ unsigned short f2bf(float f) {
  union { float f; unsigned u; } v; v.f = f;
  unsigned u = v.u;
  return (unsigned short)((u + 0x7FFF + ((u >> 16) & 1)) >> 16);
}
__device__ __forceinline__ unsigned pk2(float a, float b) {
  return (unsigned)f2bf(a) | ((unsigned)f2bf(b) << 16);
}
__device__ __forceinline__ float bflo(unsigned u) {
  union { unsigned u; float f; } v; v.u = u << 16; return v.f;
}
__device__ __forceinline__ float bfhi(unsigned u) {
  union { unsigned u; float f; } v; v.u = u & 0xffff0000u; return v.f;
}

// ---------------- edge MLP layer 1, slot-ordered (gather reads, coalesced writes) --------
__global__ __launch_bounds__(256) void k_mlp1(const float* __restrict__ ea,
    const float* __restrict__ w1, const float* __restrict__ b1,
    const int* __restrict__ elist, unsigned short* __restrict__ hes) {
  int t = threadIdx.x, w = t >> 6, j = t & 63;
  int p0 = blockIdx.x * 32 + w * 8;
  float wr[16];
#pragma unroll
  for (int i = 0; i < 16; ++i) wr[i] = w1[j * 16 + i];
  float bj = b1[j];
#pragma unroll
  for (int q = 0; q < 8; ++q) {
    int p = p0 + q;
    int e = elist[p];
    const float* a = ea + (size_t)e * 16;
    float s = bj;
#pragma unroll
    for (int i = 0; i < 16; ++i) s += a[i] * wr[i];
    hes[(size_t)p * 64 + j] = f2bf(fmaxf(s, 0.f));
  }
}

// ---------------- CSR build by dst ----------------
__global__ __launch_bounds__(256) void k_hist(const int* __restrict__ eidx,
    int* __restrict__ cnt) {
  int e = blockIdx.x * 256 + threadIdx.x;
  atomicAdd(&cnt[eidx[N_E + e]], 1);
}

__global__ __launch_bounds__(1024) void k_scan(int* __restrict__ hist,
    int* __restrict__ starts) {
  __shared__ int part[1024];
  int t = threadIdx.x;
  const int CH = 20;
  int lo = t * CH;
  int hi = lo + CH; if (hi > N_N) hi = N_N;
  int s = 0;
  for (int i = lo; i < hi; ++i) s += hist[i];
  part[t] = s;
  __syncthreads();
  for (int off = 1; off < 1024; off <<= 1) {
    int v = (t >= off) ? part[t - off] : 0;
    __syncthreads();
    part[t] += v;
    __syncthreads();
  }
  int run = (t == 0) ? 0 : part[t - 1];
  for (int i = lo; i < hi; ++i) {
    int h = hist[i];
    starts[i] = run;
    hist[i] = run;          // cursor seed
    run += h;
  }
  if (t == 1023) starts[N_N] = part[1023];
}

__global__ __launch_bounds__(256) void k_scatter(const int* __restrict__ eidx,
    int* __restrict__ cur, int* __restrict__ elist, int* __restrict__ srcl) {
  int e = blockIdx.x * 256 + threadIdx.x;
  int dn = eidx[N_E + e];
  int pos = atomicAdd(&cur[dn], 1);
  elist[pos] = e;
  srcl[pos] = eidx[e];
}

// ---------------- pack B/B2 fragment layouts + zero cursor & pool ----------------
__global__ __launch_bounds__(256) void k_pack(const float* __restrict__ w2,
    const float* __restrict__ b2f, const float* __restrict__ rootw,
    const float* __restrict__ inw,
    unsigned short* __restrict__ Bp, unsigned short* __restrict__ B2p,
    int* __restrict__ cursor, float* __restrict__ pool) {
  int idx = blockIdx.x * 256 + threadIdx.x;
  const int GT = 580 * 256;
  if (idx < 135168) {
    int i = idx & 7, l = (idx >> 3) & 63, cbkb = idx >> 9;
    int cb = cbkb & 3, kb = cbkb >> 2;
    int r = kb * 32 + ((l >> 4) << 3) + i;
    int c = (cb << 4) + (l & 15);
    float v;
    if (r < 2048) { int d = r >> 6, k = r & 63; v = w2[((d << 6) + c) * 64 + k]; }
    else if (r < 2080) v = b2f[((r - 2048) << 6) + c];
    else v = rootw[((r - 2080) << 6) + c];
    Bp[idx] = f2bf(v);
  } else if (idx < 135168 + 12288) {
    int k2 = idx - 135168;
    int i = k2 & 7, l = (k2 >> 3) & 63, cbkb = k2 >> 9;
    int cb = cbkb % 12, kb = cbkb / 12;
    int r = kb * 32 + ((l >> 4) << 3) + i;
    int c = (cb << 4) + (l & 15);
    B2p[k2] = f2bf(inw[c * 64 + r]);
  }
  for (int i = idx; i < N_N; i += GT) cursor[i] = 0;
  for (int i = idx; i < 6400; i += GT) pool[i] = 0.f;
}

// ---------------- FUSED: P-build (LDS) + MFMA GEMM (M=8) + mean/bias/relu + QKV ----------
// Block = 8 nodes, 512 threads = 8 waves, ONE wave per node (max occupancy during the
// latency-bound gather). P in LDS, chunk c of row m stored at chunk c^m.
// Phases 2/3 (GEMM+QKV, cheap) run on waves 0-3; waves 4-7 idle at barriers.
#define FMA8(hv, base, xv) \
  acc[base + 0] += xv * bflo(hv.x); acc[base + 1] += xv * bfhi(hv.x); \
  acc[base + 2] += xv * bflo(hv.y); acc[base + 3] += xv * bfhi(hv.y); \
  acc[base + 4] += xv * bflo(hv.z); acc[base + 5] += xv * bfhi(hv.z); \
  acc[base + 6] += xv * bflo(hv.w); acc[base + 7] += xv * bfhi(hv.w);

__global__ __launch_bounds__(512, 8) void k_fused(const float* __restrict__ x,
    const unsigned short* __restrict__ hes, const int* __restrict__ starts,
    const int* __restrict__ srcl,
    const unsigned short* __restrict__ Bp, const unsigned short* __restrict__ B2p,
    const float* __restrict__ convb, const float* __restrict__ inb,
    float* __restrict__ Qb, float* __restrict__ Kb, float* __restrict__ Vb) {
  __shared__ unsigned short Ps[8 * KA];      // 33,792 B
  __shared__ unsigned short xhT[8 * 68];     //  1,088 B
  int t = threadIdx.x, w = t >> 6, l = t & 63;
  int n0 = blockIdx.x * 8;
  int d0 = l >> 3, hc = (l & 7) * 8, l31 = l & 31;
  // ---- phase 1: wave w builds node n0+w ----
  {
    int m = w;
    int n = n0 + m;
    int s0 = starts[n], s1 = starts[n + 1];
    float acc[32];
#pragma unroll
    for (int z = 0; z < 32; ++z) acc[z] = 0.f;
    float xs = 0.f;
#pragma unroll 1
    for (int c0 = s0; c0 < s1; c0 += 64) {
      int srv = 0;
      if (c0 + l < s1) srv = srcl[c0 + l];
      int cc = s1 - c0; if (cc > 64) cc = 64;
#pragma unroll 1
      for (int i = 0; i < cc; i += 4) {
        uint4 h0 = {0,0,0,0}, h1 = {0,0,0,0}, h2 = {0,0,0,0}, h3 = {0,0,0,0};
        float xv0 = 0.f, xv1 = 0.f, xv2 = 0.f, xv3 = 0.f;
        int sr0 = __shfl(srv, i);
        int sr1 = __shfl(srv, i + 1);
        int sr2 = __shfl(srv, i + 2);
        int sr3 = __shfl(srv, i + 3);
        const unsigned short* hp = hes + (size_t)(c0 + i) * 64 + hc;
        h0 = *(const uint4*)hp;
        xv0 = x[(size_t)sr0 * 32 + l31];
        if (i + 1 < cc) { h1 = *(const uint4*)(hp + 64);  xv1 = x[(size_t)sr1 * 32 + l31]; }
        if (i + 2 < cc) { h2 = *(const uint4*)(hp + 128); xv2 = x[(size_t)sr2 * 32 + l31]; }
        if (i + 3 < cc) { h3 = *(const uint4*)(hp + 192); xv3 = x[(size_t)sr3 * 32 + l31]; }
        float a0 = __shfl(xv0, d0),      a1 = __shfl(xv0, d0 + 8);
        float a2 = __shfl(xv0, d0 + 16), a3 = __shfl(xv0, d0 + 24);
        FMA8(h0, 0, a0) FMA8(h0, 8, a1) FMA8(h0, 16, a2) FMA8(h0, 24, a3)
        float b0 = __shfl(xv1, d0),      b1 = __shfl(xv1, d0 + 8);
        float b2 = __shfl(xv1, d0 + 16), b3 = __shfl(xv1, d0 + 24);
        FMA8(h1, 0, b0) FMA8(h1, 8, b1) FMA8(h1, 16, b2) FMA8(h1, 24, b3)
        float c0f = __shfl(xv2, d0),      c1f = __shfl(xv2, d0 + 8);
        float c2f = __shfl(xv2, d0 + 16), c3f = __shfl(xv2, d0 + 24);
        FMA8(h2, 0, c0f) FMA8(h2, 8, c1f) FMA8(h2, 16, c2f) FMA8(h2, 24, c3f)
        float e0 = __shfl(xv3, d0),      e1 = __shfl(xv3, d0 + 8);
        float e2 = __shfl(xv3, d0 + 16), e3 = __shfl(xv3, d0 + 24);
        FMA8(h3, 0, e0) FMA8(h3, 8, e1) FMA8(h3, 16, e2) FMA8(h3, 24, e3)
        xs += xv0 + xv1 + xv2 + xv3;
      }
    }
    int s = m;
#pragma unroll
    for (int q = 0; q < 4; ++q) {
      int scr = (l + 64 * q) ^ s;
      uint4 o;
      o.x = pk2(acc[q * 8 + 0], acc[q * 8 + 1]);
      o.y = pk2(acc[q * 8 + 2], acc[q * 8 + 3]);
      o.z = pk2(acc[q * 8 + 4], acc[q * 8 + 5]);
      o.w = pk2(acc[q * 8 + 6], acc[q * 8 + 7]);
      *(uint4*)(Ps + m * KA + scr * 8) = o;
    }
    if (l < 32) {
      int cnt = s1 - s0; if (cnt < 1) cnt = 1;
      int c1 = (256 + (l >> 3)) ^ s, c2 = (260 + (l >> 3)) ^ s;
      Ps[m * KA + c1 * 8 + (l & 7)] = f2bf(xs);
      Ps[m * KA + c2 * 8 + (l & 7)] = f2bf(x[(size_t)n * 32 + l] * (float)cnt);
    }
  }
  __syncthreads();
  // ---- phase 2: GEMM K-loop (M=8, rows duplicated), waves 0-3 own cols w*16..+16 ----
  int col = l & 15, sub = l >> 4;
  int arow = col & 7;
  if (w < 4) {
    const bfrag* Bb = (const bfrag*)Bp + w * 64 + l;
    facc ac = {0.f, 0.f, 0.f, 0.f};
#pragma unroll 4
    for (int kb = 0; kb < NKB; ++kb) {
      int scr = ((kb << 2) + sub) ^ arow;
      bfrag af = *(const bfrag*)(Ps + arow * KA + scr * 8);
      ac = __builtin_amdgcn_mfma_f32_16x16x32_bf16(af, Bb[kb * 256], ac, 0, 0, 0);
    }
    float cv = convb[w * 16 + col];
#pragma unroll
    for (int j = 0; j < 4; ++j) {
      int m = sub * 4 + j;
      if (m < 8) {
        int n = n0 + m;
        int cnt = starts[n + 1] - starts[n]; if (cnt < 1) cnt = 1;
        float inv = 1.f / (float)cnt;
        xhT[m * 68 + w * 16 + col] = f2bf(fmaxf(ac[j] * inv + cv, 0.f));
      }
    }
  }
  __syncthreads();
  // ---- phase 3: QKV (M=8), waves 0-3 own 3 of 12 col blocks ----
  if (w < 4) {
    bfrag af0 = *(const bfrag*)&xhT[(col & 7) * 68 + sub * 8];
    bfrag af1 = *(const bfrag*)&xhT[(col & 7) * 68 + 32 + sub * 8];
    const bfrag* B2b = (const bfrag*)B2p + l;
#pragma unroll
    for (int c3 = 0; c3 < 3; ++c3) {
      int cb = w * 3 + c3;
      facc qa = {0.f, 0.f, 0.f, 0.f};
      qa = __builtin_amdgcn_mfma_f32_16x16x32_bf16(af0, B2b[cb * 64], qa, 0, 0, 0);
      qa = __builtin_amdgcn_mfma_f32_16x16x32_bf16(af1, B2b[(12 + cb) * 64], qa, 0, 0, 0);
#pragma unroll
      for (int j = 0; j < 4; ++j) {
        int m = sub * 4 + j;
        if (m < 8) {
          int n = n0 + m;
          int g = n / 200, p = n - g * 200;
          int c = cb * 16 + col;
          float v = qa[j] + inb[c];
          int part = c >> 6, rem = c & 63, hh = rem >> 4, dd = rem & 15;
          float* dst = (part == 0) ? Qb : (part == 1 ? Kb : Vb);
          dst[(((size_t)g * 4 + hh) * 200 + p) * 16 + dd] = v;
        }
      }
    }
  }
}

// ---------------- MFMA flash attention + fused linear pooling ----------------
// Two blocks per (graph, head); each accumulates its column-sums into pool[G*64].
__global__ __launch_bounds__(256) void k_attn(const float* __restrict__ Qb,
    const float* __restrict__ Kb, const float* __restrict__ Vb,
    float* __restrict__ pool) {
  __shared__ unsigned short Ks[224 * 24];
  __shared__ unsigned short Vt[16 * 232];
  __shared__ unsigned short Pl[4][16 * 40];
  __shared__ float pw[4][16];
  int t = threadIdx.x;
  int gh = blockIdx.x >> 1, half = blockIdx.x & 1;
  size_t base = (size_t)gh * 3200;
  for (int idx = t; idx < 224 * 16; idx += 256) {
    int row = idx >> 4, d = idx & 15;
    float kv = (row < 200) ? Kb[base + idx] : 0.f;
    float vv = (row < 200) ? Vb[base + idx] : 0.f;
    Ks[row * 24 + d] = f2bf(kv);
    Vt[d * 232 + row] = f2bf(vv);
  }
  __syncthreads();
  int w = t >> 6, l = t & 63;
  int sub = l >> 4, col = l & 15;
  int qlo = half * 7, qhi = half ? 13 : 7;
  float pacc = 0.f;
  for (int qt = qlo + w; qt < qhi; qt += 4) {
    bfrag qf = {0, 0, 0, 0, 0, 0, 0, 0};
    int q = qt * 16 + col;
    if (sub < 2 && q < 200) {
      const float* qp = Qb + base + q * 16 + sub * 8;
      float4 qa = *(const float4*)qp;
      float4 qb = *(const float4*)(qp + 4);
      qf[0] = (short)f2bf(qa.x); qf[1] = (short)f2bf(qa.y);
      qf[2] = (short)f2bf(qa.z); qf[3] = (short)f2bf(qa.w);
      qf[4] = (short)f2bf(qb.x); qf[5] = (short)f2bf(qb.y);
      qf[6] = (short)f2bf(qb.z); qf[7] = (short)f2bf(qb.w);
    }
    facc o = {0.f, 0.f, 0.f, 0.f};
    float srow0 = 0.f, srow1 = 0.f, srow2 = 0.f, srow3 = 0.f;
    for (int kt2 = 0; kt2 < 7; ++kt2) {
      int kt0 = kt2 * 2, kt1 = kt0 + 1;
      bfrag kf0 = {0, 0, 0, 0, 0, 0, 0, 0};
      bfrag kf1 = {0, 0, 0, 0, 0, 0, 0, 0};
      if (sub < 2) {
        kf0 = *(const bfrag*)&Ks[(kt0 * 16 + col) * 24 + sub * 8];
        kf1 = *(const bfrag*)&Ks[(kt1 * 16 + col) * 24 + sub * 8];
      }
      facc z = {0.f, 0.f, 0.f, 0.f};
      facc s0 = __builtin_amdgcn_mfma_f32_16x16x32_bf16(qf, kf0, z, 0, 0, 0);
      facc s1 = __builtin_amdgcn_mfma_f32_16x16x32_bf16(qf, kf1, z, 0, 0, 0);
      bool ok0 = (kt0 * 16 + col) < 200;
      bool ok1 = (kt1 * 16 + col) < 200;
#pragma unroll
      for (int j = 0; j < 4; ++j) {
        float e0 = ok0 ? __expf(s0[j] * 0.25f) : 0.f;
        float e1 = ok1 ? __expf(s1[j] * 0.25f) : 0.f;
        if (j == 0) { srow0 += e0 + e1; } else if (j == 1) { srow1 += e0 + e1; }
        else if (j == 2) { srow2 += e0 + e1; } else { srow3 += e0 + e1; }
        int qr = (sub << 2) + j;
        Pl[w][qr * 40 + col] = f2bf(e0);
        Pl[w][qr * 40 + 16 + col] = f2bf(e1);
      }
      bfrag pf = *(const bfrag*)&Pl[w][col * 40 + sub * 8];
      bfrag vf = *(const bfrag*)&Vt[col * 232 + kt2 * 32 + sub * 8];
      o = __builtin_amdgcn_mfma_f32_16x16x32_bf16(pf, vf, o, 0, 0, 0);
    }
#pragma unroll
    for (int off = 1; off < 16; off <<= 1) {
      srow0 += __shfl_xor(srow0, off);
      srow1 += __shfl_xor(srow1, off);
      srow2 += __shfl_xor(srow2, off);
      srow3 += __shfl_xor(srow3, off);
    }
#pragma unroll
    for (int j = 0; j < 4; ++j) {
      int qq = qt * 16 + (sub << 2) + j;
      float sr = (j == 0) ? srow0 : (j == 1) ? srow1 : (j == 2) ? srow2 : srow3;
      if (qq < 200) pacc += o[j] / sr;
    }
  }
  // reduce pacc over the 4 sub-lanes with the same col, then across waves
  pacc += __shfl_xor(pacc, 16);
  pacc += __shfl_xor(pacc, 32);
  if (l < 16) pw[w][l] = pacc;
  __syncthreads();
  if (t < 16) {
    float v = pw[0][t] + pw[1][t] + pw[2][t] + pw[3][t];
    atomicAdd(&pool[gh * 16 + t], v);
  }
}

// ---------------- head: out_proj(pool/200) + MLP ----------------
__global__ __launch_bounds__(64) void k_head(const float* __restrict__ pool,
    const float* __restrict__ ow, const float* __restrict__ ob,
    const float* __restrict__ w1, const float* __restrict__ b1,
    const float* __restrict__ w2, const float* __restrict__ b2,
    float* __restrict__ out) {
  __shared__ float ms[64], es[64];
  int g = blockIdx.x, t = threadIdx.x;
  ms[t] = pool[g * 64 + t] * (1.f / 200.f);
  __syncthreads();
  float e = ob[t];
  for (int j = 0; j < 64; ++j) e += ow[t * 64 + j] * ms[j];
  es[t] = e;
  __syncthreads();
  float h1 = b1[t];
  for (int j = 0; j < 64; ++j) h1 += w1[t * 64 + j] * es[j];
  h1 = fmaxf(h1, 0.f);
  float pr = h1 * w2[t];
  for (int off = 32; off >= 1; off >>= 1) pr += __shfl_xor(pr, off);
  if (t == 0) out[g] = pr + b2[0];
}

extern "C" void kernel_launch(void* const* d_in, const int* in_sizes, int n_in,
                              void* d_out, int out_size, void* d_ws, size_t ws_size,
                              hipStream_t stream) {
  (void)in_sizes; (void)n_in;
  const float* x      = (const float*)d_in[0];
  const int*   eidx   = (const int*)d_in[1];
  const float* ea     = (const float*)d_in[2];
  const float* en_w1  = (const float*)d_in[4];
  const float* en_b1  = (const float*)d_in[5];
  const float* en_w2  = (const float*)d_in[6];
  const float* en_b2  = (const float*)d_in[7];
  const float* root_w = (const float*)d_in[8];
  const float* conv_b = (const float*)d_in[9];
  const float* in_w   = (const float*)d_in[10];
  const float* in_b   = (const float*)d_in[11];
  const float* out_w  = (const float*)d_in[12];
  const float* out_b  = (const float*)d_in[13];
  const float* l1w    = (const float*)d_in[14];
  const float* l1b    = (const float*)d_in[15];
  const float* l2w    = (const float*)d_in[16];
  const float* l2b    = (const float*)d_in[17];
  float* out = (float*)d_out;

  // ---- workspace layout (bytes) ----
  char* w = (char*)d_ws;
  unsigned short* hes = (unsigned short*)w;            // 20,480,000 (dst-sorted he)
  float* Qb  = (float*)(w + 20480000);
  float* Kb  = (float*)(w + 25600000);
  float* Vb  = (float*)(w + 30720000);
  float* pool = (float*)(w + 35840000);                // 25,600 B
  char* r3 = w + 35870000;
  unsigned short* Bp  = (unsigned short*)r3;             // 270,336
  unsigned short* B2p = (unsigned short*)(r3 + 270336);  // 24,576
  int* starts = (int*)(r3 + 270336 + 24576);
  int* elist  = starts + (N_N + 4);
  int* srcl   = elist + N_E;
  int* cursor = srcl + N_E;
  size_t need = 35870000 + 270336 + 24576
              + (size_t)(N_N + 4) * 4 + 2 * (size_t)N_E * 4 + (size_t)N_N * 4;
  if (ws_size < need || out_size < 100) return;

  k_pack<<<580, 256, 0, stream>>>(en_w2, en_b2, root_w, in_w, Bp, B2p, cursor, pool);
  k_hist<<<N_E / 256, 256, 0, stream>>>(eidx, cursor);
  k_scan<<<1, 1024, 0, stream>>>(cursor, starts);
  k_scatter<<<N_E / 256, 256, 0, stream>>>(eidx, cursor, elist, srcl);
  k_mlp1<<<5000, 256, 0, stream>>>(ea, en_w1, en_b1, elist, hes);
  k_fused<<<2500, 512, 0, stream>>>(x, hes, starts, srcl, Bp, B2p,
                                    conv_b, in_b, Qb, Kb, Vb);
  k_attn<<<800, 256, 0, stream>>>(Qb, Kb, Vb, pool);
  k_head<<<100, 64, 0, stream>>>(pool, out_w, out_b, l1w, l1b, l2w, l2b, out);
}

// Round 14
// 173.356 us; speedup vs baseline: 2.7691x; 1.7175x over previous
//
#include <hip/hip_runtime.h>
#include <math.h>

#define N_N 20000
#define N_E 160000
#define KA 2112   // A cols: 2048 (P) + 32 (xsum for b2) + 32 (x*cnt for root_w)
#define NKB 66

typedef __attribute__((ext_vector_type(8))) short bfrag;
typedef __attribute__((ext_vector_type(4))) float facc;

__device__ __forceinline__ unsigned short f2bf(float f) {
  union { float f; unsigned u; } v; v.f = f;
  unsigned u = v.u;
  return (unsigned short)((u + 0x7FFF + ((u >> 16) & 1)) >> 16);
}
__device__ __forceinline__ unsigned pk2(float a, float b) {
  return (unsigned)f2bf(a) | ((unsigned)f2bf(b) << 16);
}
__device__ __forceinline__ float bflo(unsigned u) {
  union { unsigned u; float f; } v; v.u = u << 16; return v.f;
}
__device__ __forceinline__ float bfhi(unsigned u) {
  union { unsigned u; float f; } v; v.u = u & 0xffff0000u; return v.f;
}

// ---------------- edge MLP layer 1, slot-ordered (gather reads, coalesced writes) --------
__global__ __launch_bounds__(256) void k_mlp1(const float* __restrict__ ea,
    const float* __restrict__ w1, const float* __restrict__ b1,
    const int* __restrict__ elist, unsigned short* __restrict__ hes) {
  int t = threadIdx.x, w = t >> 6, j = t & 63;
  int p0 = blockIdx.x * 32 + w * 8;
  float wr[16];
#pragma unroll
  for (int i = 0; i < 16; ++i) wr[i] = w1[j * 16 + i];
  float bj = b1[j];
#pragma unroll
  for (int q = 0; q < 8; ++q) {
    int p = p0 + q;
    int e = elist[p];
    const float* a = ea + (size_t)e * 16;
    float s = bj;
#pragma unroll
    for (int i = 0; i < 16; ++i) s += a[i] * wr[i];
    hes[(size_t)p * 64 + j] = f2bf(fmaxf(s, 0.f));
  }
}

// ---------------- CSR build by dst ----------------
__global__ __launch_bounds__(256) void k_hist(const int* __restrict__ eidx,
    int* __restrict__ cnt) {
  int e = blockIdx.x * 256 + threadIdx.x;
  atomicAdd(&cnt[eidx[N_E + e]], 1);
}

__global__ __launch_bounds__(1024) void k_scan(int* __restrict__ hist,
    int* __restrict__ starts) {
  __shared__ int part[1024];
  int t = threadIdx.x;
  const int CH = 20;
  int lo = t * CH;
  int hi = lo + CH; if (hi > N_N) hi = N_N;
  int s = 0;
  for (int i = lo; i < hi; ++i) s += hist[i];
  part[t] = s;
  __syncthreads();
  for (int off = 1; off < 1024; off <<= 1) {
    int v = (t >= off) ? part[t - off] : 0;
    __syncthreads();
    part[t] += v;
    __syncthreads();
  }
  int run = (t == 0) ? 0 : part[t - 1];
  for (int i = lo; i < hi; ++i) {
    int h = hist[i];
    starts[i] = run;
    hist[i] = run;          // cursor seed
    run += h;
  }
  if (t == 1023) starts[N_N] = part[1023];
}

__global__ __launch_bounds__(256) void k_scatter(const int* __restrict__ eidx,
    int* __restrict__ cur, int* __restrict__ elist, int* __restrict__ srcl) {
  int e = blockIdx.x * 256 + threadIdx.x;
  int dn = eidx[N_E + e];
  int pos = atomicAdd(&cur[dn], 1);
  elist[pos] = e;
  srcl[pos] = eidx[e];
}

// ---------------- pack B/B2 fragment layouts + zero cursor & pool ----------------
__global__ __launch_bounds__(256) void k_pack(const float* __restrict__ w2,
    const float* __restrict__ b2f, const float* __restrict__ rootw,
    const float* __restrict__ inw,
    unsigned short* __restrict__ Bp, unsigned short* __restrict__ B2p,
    int* __restrict__ cursor, float* __restrict__ pool) {
  int idx = blockIdx.x * 256 + threadIdx.x;
  const int GT = 580 * 256;
  if (idx < 135168) {
    int i = idx & 7, l = (idx >> 3) & 63, cbkb = idx >> 9;
    int cb = cbkb & 3, kb = cbkb >> 2;
    int r = kb * 32 + ((l >> 4) << 3) + i;
    int c = (cb << 4) + (l & 15);
    float v;
    if (r < 2048) { int d = r >> 6, k = r & 63; v = w2[((d << 6) + c) * 64 + k]; }
    else if (r < 2080) v = b2f[((r - 2048) << 6) + c];
    else v = rootw[((r - 2080) << 6) + c];
    Bp[idx] = f2bf(v);
  } else if (idx < 135168 + 12288) {
    int k2 = idx - 135168;
    int i = k2 & 7, l = (k2 >> 3) & 63, cbkb = k2 >> 9;
    int cb = cbkb % 12, kb = cbkb / 12;
    int r = kb * 32 + ((l >> 4) << 3) + i;
    int c = (cb << 4) + (l & 15);
    B2p[k2] = f2bf(inw[c * 64 + r]);
  }
  for (int i = idx; i < N_N; i += GT) cursor[i] = 0;
  for (int i = idx; i < 6400; i += GT) pool[i] = 0.f;
}

// ---------------- FUSED: P-build (LDS) + MFMA GEMM (M=8) + mean/bias/relu + QKV ----------
// Block = 8 nodes, 512 threads = 8 waves, ONE wave per node.
// __launch_bounds__(512, 4): VGPR cap 128 (compiler lands ~64) -> no spill; LDS 35 KB ->
// 4 blocks/CU x 8 waves = 32 waves/CU when VGPR <= 64.
#define FMA8(hv, base, xv) \
  acc[base + 0] += xv * bflo(hv.x); acc[base + 1] += xv * bfhi(hv.x); \
  acc[base + 2] += xv * bflo(hv.y); acc[base + 3] += xv * bfhi(hv.y); \
  acc[base + 4] += xv * bflo(hv.z); acc[base + 5] += xv * bfhi(hv.z); \
  acc[base + 6] += xv * bflo(hv.w); acc[base + 7] += xv * bfhi(hv.w);

__global__ __launch_bounds__(512, 4) void k_fused(const float* __restrict__ x,
    const unsigned short* __restrict__ hes, const int* __restrict__ starts,
    const int* __restrict__ srcl,
    const unsigned short* __restrict__ Bp, const unsigned short* __restrict__ B2p,
    const float* __restrict__ convb, const float* __restrict__ inb,
    float* __restrict__ Qb, float* __restrict__ Kb, float* __restrict__ Vb) {
  __shared__ unsigned short Ps[8 * KA];      // 33,792 B
  __shared__ unsigned short xhT[8 * 68];     //  1,088 B
  int t = threadIdx.x, w = t >> 6, l = t & 63;
  int n0 = blockIdx.x * 8;
  int d0 = l >> 3, hc = (l & 7) * 8, l31 = l & 31;
  // ---- phase 1: wave w builds node n0+w ----
  {
    int m = w;
    int n = n0 + m;
    int s0 = starts[n], s1 = starts[n + 1];
    float acc[32];
#pragma unroll
    for (int z = 0; z < 32; ++z) acc[z] = 0.f;
    float xs = 0.f;
#pragma unroll 1
    for (int c0 = s0; c0 < s1; c0 += 64) {
      int srv = 0;
      if (c0 + l < s1) srv = srcl[c0 + l];
      int cc = s1 - c0; if (cc > 64) cc = 64;
#pragma unroll 1
      for (int i = 0; i < cc; i += 4) {
        uint4 h0 = {0,0,0,0}, h1 = {0,0,0,0}, h2 = {0,0,0,0}, h3 = {0,0,0,0};
        float xv0 = 0.f, xv1 = 0.f, xv2 = 0.f, xv3 = 0.f;
        int sr0 = __shfl(srv, i);
        int sr1 = __shfl(srv, i + 1);
        int sr2 = __shfl(srv, i + 2);
        int sr3 = __shfl(srv, i + 3);
        const unsigned short* hp = hes + (size_t)(c0 + i) * 64 + hc;
        h0 = *(const uint4*)hp;
        xv0 = x[(size_t)sr0 * 32 + l31];
        if (i + 1 < cc) { h1 = *(const uint4*)(hp + 64);  xv1 = x[(size_t)sr1 * 32 + l31]; }
        if (i + 2 < cc) { h2 = *(const uint4*)(hp + 128); xv2 = x[(size_t)sr2 * 32 + l31]; }
        if (i + 3 < cc) { h3 = *(const uint4*)(hp + 192); xv3 = x[(size_t)sr3 * 32 + l31]; }
        float a0 = __shfl(xv0, d0),      a1 = __shfl(xv0, d0 + 8);
        float a2 = __shfl(xv0, d0 + 16), a3 = __shfl(xv0, d0 + 24);
        FMA8(h0, 0, a0) FMA8(h0, 8, a1) FMA8(h0, 16, a2) FMA8(h0, 24, a3)
        float b0 = __shfl(xv1, d0),      b1 = __shfl(xv1, d0 + 8);
        float b2 = __shfl(xv1, d0 + 16), b3 = __shfl(xv1, d0 + 24);
        FMA8(h1, 0, b0) FMA8(h1, 8, b1) FMA8(h1, 16, b2) FMA8(h1, 24, b3)
        float c0f = __shfl(xv2, d0),      c1f = __shfl(xv2, d0 + 8);
        float c2f = __shfl(xv2, d0 + 16), c3f = __shfl(xv2, d0 + 24);
        FMA8(h2, 0, c0f) FMA8(h2, 8, c1f) FMA8(h2, 16, c2f) FMA8(h2, 24, c3f)
        float e0 = __shfl(xv3, d0),      e1 = __shfl(xv3, d0 + 8);
        float e2 = __shfl(xv3, d0 + 16), e3 = __shfl(xv3, d0 + 24);
        FMA8(h3, 0, e0) FMA8(h3, 8, e1) FMA8(h3, 16, e2) FMA8(h3, 24, e3)
        xs += xv0 + xv1 + xv2 + xv3;
      }
    }
    int s = m;
#pragma unroll
    for (int q = 0; q < 4; ++q) {
      int scr = (l + 64 * q) ^ s;
      uint4 o;
      o.x = pk2(acc[q * 8 + 0], acc[q * 8 + 1]);
      o.y = pk2(acc[q * 8 + 2], acc[q * 8 + 3]);
      o.z = pk2(acc[q * 8 + 4], acc[q * 8 + 5]);
      o.w = pk2(acc[q * 8 + 6], acc[q * 8 + 7]);
      *(uint4*)(Ps + m * KA + scr * 8) = o;
    }
    if (l < 32) {
      int cnt = s1 - s0; if (cnt < 1) cnt = 1;
      int c1 = (256 + (l >> 3)) ^ s, c2 = (260 + (l >> 3)) ^ s;
      Ps[m * KA + c1 * 8 + (l & 7)] = f2bf(xs);
      Ps[m * KA + c2 * 8 + (l & 7)] = f2bf(x[(size_t)n * 32 + l] * (float)cnt);
    }
  }
  __syncthreads();
  // ---- phase 2: GEMM K-loop (M=8, rows duplicated), waves 0-3 own cols w*16..+16 ----
  int col = l & 15, sub = l >> 4;
  int arow = col & 7;
  if (w < 4) {
    const bfrag* Bb = (const bfrag*)Bp + w * 64 + l;
    facc ac = {0.f, 0.f, 0.f, 0.f};
#pragma unroll 4
    for (int kb = 0; kb < NKB; ++kb) {
      int scr = ((kb << 2) + sub) ^ arow;
      bfrag af = *(const bfrag*)(Ps + arow * KA + scr * 8);
      ac = __builtin_amdgcn_mfma_f32_16x16x32_bf16(af, Bb[kb * 256], ac, 0, 0, 0);
    }
    float cv = convb[w * 16 + col];
#pragma unroll
    for (int j = 0; j < 4; ++j) {
      int m = sub * 4 + j;
      if (m < 8) {
        int n = n0 + m;
        int cnt = starts[n + 1] - starts[n]; if (cnt < 1) cnt = 1;
        float inv = 1.f / (float)cnt;
        xhT[m * 68 + w * 16 + col] = f2bf(fmaxf(ac[j] * inv + cv, 0.f));
      }
    }
  }
  __syncthreads();
  // ---- phase 3: QKV (M=8), waves 0-3 own 3 of 12 col blocks ----
  if (w < 4) {
    bfrag af0 = *(const bfrag*)&xhT[(col & 7) * 68 + sub * 8];
    bfrag af1 = *(const bfrag*)&xhT[(col & 7) * 68 + 32 + sub * 8];
    const bfrag* B2b = (const bfrag*)B2p + l;
#pragma unroll
    for (int c3 = 0; c3 < 3; ++c3) {
      int cb = w * 3 + c3;
      facc qa = {0.f, 0.f, 0.f, 0.f};
      qa = __builtin_amdgcn_mfma_f32_16x16x32_bf16(af0, B2b[cb * 64], qa, 0, 0, 0);
      qa = __builtin_amdgcn_mfma_f32_16x16x32_bf16(af1, B2b[(12 + cb) * 64], qa, 0, 0, 0);
#pragma unroll
      for (int j = 0; j < 4; ++j) {
        int m = sub * 4 + j;
        if (m < 8) {
          int n = n0 + m;
          int g = n / 200, p = n - g * 200;
          int c = cb * 16 + col;
          float v = qa[j] + inb[c];
          int part = c >> 6, rem = c & 63, hh = rem >> 4, dd = rem & 15;
          float* dst = (part == 0) ? Qb : (part == 1 ? Kb : Vb);
          dst[(((size_t)g * 4 + hh) * 200 + p) * 16 + dd] = v;
        }
      }
    }
  }
}

// ---------------- MFMA flash attention + fused linear pooling ----------------
// Two blocks per (graph, head); each accumulates its column-sums into pool[G*64].
__global__ __launch_bounds__(256) void k_attn(const float* __restrict__ Qb,
    const float* __restrict__ Kb, const float* __restrict__ Vb,
    float* __restrict__ pool) {
  __shared__ unsigned short Ks[224 * 24];
  __shared__ unsigned short Vt[16 * 232];
  __shared__ unsigned short Pl[4][16 * 40];
  __shared__ float pw[4][16];
  int t = threadIdx.x;
  int gh = blockIdx.x >> 1, half = blockIdx.x & 1;
  size_t base = (size_t)gh * 3200;
  for (int idx = t; idx < 224 * 16; idx += 256) {
    int row = idx >> 4, d = idx & 15;
    float kv = (row < 200) ? Kb[base + idx] : 0.f;
    float vv = (row < 200) ? Vb[base + idx] : 0.f;
    Ks[row * 24 + d] = f2bf(kv);
    Vt[d * 232 + row] = f2bf(vv);
  }
  __syncthreads();
  int w = t >> 6, l = t & 63;
  int sub = l >> 4, col = l & 15;
  int qlo = half * 7, qhi = half ? 13 : 7;
  float pacc = 0.f;
  for (int qt = qlo + w; qt < qhi; qt += 4) {
    bfrag qf = {0, 0, 0, 0, 0, 0, 0, 0};
    int q = qt * 16 + col;
    if (sub < 2 && q < 200) {
      const float* qp = Qb + base + q * 16 + sub * 8;
      float4 qa = *(const float4*)qp;
      float4 qb = *(const float4*)(qp + 4);
      qf[0] = (short)f2bf(qa.x); qf[1] = (short)f2bf(qa.y);
      qf[2] = (short)f2bf(qa.z); qf[3] = (short)f2bf(qa.w);
      qf[4] = (short)f2bf(qb.x); qf[5] = (short)f2bf(qb.y);
      qf[6] = (short)f2bf(qb.z); qf[7] = (short)f2bf(qb.w);
    }
    facc o = {0.f, 0.f, 0.f, 0.f};
    float srow0 = 0.f, srow1 = 0.f, srow2 = 0.f, srow3 = 0.f;
    for (int kt2 = 0; kt2 < 7; ++kt2) {
      int kt0 = kt2 * 2, kt1 = kt0 + 1;
      bfrag kf0 = {0, 0, 0, 0, 0, 0, 0, 0};
      bfrag kf1 = {0, 0, 0, 0, 0, 0, 0, 0};
      if (sub < 2) {
        kf0 = *(const bfrag*)&Ks[(kt0 * 16 + col) * 24 + sub * 8];
        kf1 = *(const bfrag*)&Ks[(kt1 * 16 + col) * 24 + sub * 8];
      }
      facc z = {0.f, 0.f, 0.f, 0.f};
      facc s0 = __builtin_amdgcn_mfma_f32_16x16x32_bf16(qf, kf0, z, 0, 0, 0);
      facc s1 = __builtin_amdgcn_mfma_f32_16x16x32_bf16(qf, kf1, z, 0, 0, 0);
      bool ok0 = (kt0 * 16 + col) < 200;
      bool ok1 = (kt1 * 16 + col) < 200;
#pragma unroll
      for (int j = 0; j < 4; ++j) {
        float e0 = ok0 ? __expf(s0[j] * 0.25f) : 0.f;
        float e1 = ok1 ? __expf(s1[j] * 0.25f) : 0.f;
        if (j == 0) { srow0 += e0 + e1; } else if (j == 1) { srow1 += e0 + e1; }
        else if (j == 2) { srow2 += e0 + e1; } else { srow3 += e0 + e1; }
        int qr = (sub << 2) + j;
        Pl[w][qr * 40 + col] = f2bf(e0);
        Pl[w][qr * 40 + 16 + col] = f2bf(e1);
      }
      bfrag pf = *(const bfrag*)&Pl[w][col * 40 + sub * 8];
      bfrag vf = *(const bfrag*)&Vt[col * 232 + kt2 * 32 + sub * 8];
      o = __builtin_amdgcn_mfma_f32_16x16x32_bf16(pf, vf, o, 0, 0, 0);
    }
#pragma unroll
    for (int off = 1; off < 16; off <<= 1) {
      srow0 += __shfl_xor(srow0, off);
      srow1 += __shfl_xor(srow1, off);
      srow2 += __shfl_xor(srow2, off);
      srow3 += __shfl_xor(srow3, off);
    }
#pragma unroll
    for (int j = 0; j < 4; ++j) {
      int qq = qt * 16 + (sub << 2) + j;
      float sr = (j == 0) ? srow0 : (j == 1) ? srow1 : (j == 2) ? srow2 : srow3;
      if (qq < 200) pacc += o[j] / sr;
    }
  }
  // reduce pacc over the 4 sub-lanes with the same col, then across waves
  pacc += __shfl_xor(pacc, 16);
  pacc += __shfl_xor(pacc, 32);
  if (l < 16) pw[w][l] = pacc;
  __syncthreads();
  if (t < 16) {
    float v = pw[0][t] + pw[1][t] + pw[2][t] + pw[3][t];
    atomicAdd(&pool[gh * 16 + t], v);
  }
}

// ---------------- head: out_proj(pool/200) + MLP ----------------
__global__ __launch_bounds__(64) void k_head(const float* __restrict__ pool,
    const float* __restrict__ ow, const float* __restrict__ ob,
    const float* __restrict__ w1, const float* __restrict__ b1,
    const float* __restrict__ w2, const float* __restrict__ b2,
    float* __restrict__ out) {
  __shared__ float ms[64], es[64];
  int g = blockIdx.x, t = threadIdx.x;
  ms[t] = pool[g * 64 + t] * (1.f / 200.f);
  __syncthreads();
  float e = ob[t];
  for (int j = 0; j < 64; ++j) e += ow[t * 64 + j] * ms[j];
  es[t] = e;
  __syncthreads();
  float h1 = b1[t];
  for (int j = 0; j < 64; ++j) h1 += w1[t * 64 + j] * es[j];
  h1 = fmaxf(h1, 0.f);
  float pr = h1 * w2[t];
  for (int off = 32; off >= 1; off >>= 1) pr += __shfl_xor(pr, off);
  if (t == 0) out[g] = pr + b2[0];
}

extern "C" void kernel_launch(void* const* d_in, const int* in_sizes, int n_in,
                              void* d_out, int out_size, void* d_ws, size_t ws_size,
                              hipStream_t stream) {
  (void)in_sizes; (void)n_in;
  const float* x      = (const float*)d_in[0];
  const int*   eidx   = (const int*)d_in[1];
  const float* ea     = (const float*)d_in[2];
  const float* en_w1  = (const float*)d_in[4];
  const float* en_b1  = (const float*)d_in[5];
  const float* en_w2  = (const float*)d_in[6];
  const float* en_b2  = (const float*)d_in[7];
  const float* root_w = (const float*)d_in[8];
  const float* conv_b = (const float*)d_in[9];
  const float* in_w   = (const float*)d_in[10];
  const float* in_b   = (const float*)d_in[11];
  const float* out_w  = (const float*)d_in[12];
  const float* out_b  = (const float*)d_in[13];
  const float* l1w    = (const float*)d_in[14];
  const float* l1b    = (const float*)d_in[15];
  const float* l2w    = (const float*)d_in[16];
  const float* l2b    = (const float*)d_in[17];
  float* out = (float*)d_out;

  // ---- workspace layout (bytes) ----
  char* w = (char*)d_ws;
  unsigned short* hes = (unsigned short*)w;            // 20,480,000 (dst-sorted he)
  float* Qb  = (float*)(w + 20480000);
  float* Kb  = (float*)(w + 25600000);
  float* Vb  = (float*)(w + 30720000);
  float* pool = (float*)(w + 35840000);                // 25,600 B
  char* r3 = w + 35870000;
  unsigned short* Bp  = (unsigned short*)r3;             // 270,336
  unsigned short* B2p = (unsigned short*)(r3 + 270336);  // 24,576
  int* starts = (int*)(r3 + 270336 + 24576);
  int* elist  = starts + (N_N + 4);
  int* srcl   = elist + N_E;
  int* cursor = srcl + N_E;
  size_t need = 35870000 + 270336 + 24576
              + (size_t)(N_N + 4) * 4 + 2 * (size_t)N_E * 4 + (size_t)N_N * 4;
  if (ws_size < need || out_size < 100) return;

  k_pack<<<580, 256, 0, stream>>>(en_w2, en_b2, root_w, in_w, Bp, B2p, cursor, pool);
  k_hist<<<N_E / 256, 256, 0, stream>>>(eidx, cursor);
  k_scan<<<1, 1024, 0, stream>>>(cursor, starts);
  k_scatter<<<N_E / 256, 256, 0, stream>>>(eidx, cursor, elist, srcl);
  k_mlp1<<<5000, 256, 0, stream>>>(ea, en_w1, en_b1, elist, hes);
  k_fused<<<2500, 512, 0, stream>>>(x, hes, starts, srcl, Bp, B2p,
                                    conv_b, in_b, Qb, Kb, Vb);
  k_attn<<<800, 256, 0, stream>>>(Qb, Kb, Vb, pool);
  k_head<<<100, 64, 0, stream>>>(pool, out_w, out_b, l1w, l1b, l2w, l2b, out);
}

// Round 15
// 165.087 us; speedup vs baseline: 2.9078x; 1.0501x over previous
//
#include <hip/hip_runtime.h>
#include <math.h>

#define N_N 20000
#define N_E 160000
#define KA 2112   // A cols: 2048 (P) + 32 (xsum for b2) + 32 (x*cnt for root_w)
#define NKB 66

typedef __attribute__((ext_vector_type(8))) short bfrag;
typedef __attribute__((ext_vector_type(4))) float facc;

__device__ __forceinline__ unsigned short f2bf(float f) {
  union { float f; unsigned u; } v; v.f = f;
  unsigned u = v.u;
  return (unsigned short)((u + 0x7FFF + ((u >> 16) & 1)) >> 16);
}
__device__ __forceinline__ unsigned pk2(float a, float b) {
  return (unsigned)f2bf(a) | ((unsigned)f2bf(b) << 16);
}
__device__ __forceinline__ float bflo(unsigned u) {
  union { unsigned u; float f; } v; v.u = u << 16; return v.f;
}
__device__ __forceinline__ float bfhi(unsigned u) {
  union { unsigned u; float f; } v; v.u = u & 0xffff0000u; return v.f;
}
// async global->LDS, 16B per lane; LDS dest = wave-uniform base + lane*16
__device__ __forceinline__ void gload16(const void* g, void* s) {
  __builtin_amdgcn_global_load_lds(
      (const __attribute__((address_space(1))) void*)g,
      (__attribute__((address_space(3))) void*)s, 16, 0, 0);
}

// ---------------- edge MLP layer 1, slot-ordered (gather reads, coalesced writes) --------
__global__ __launch_bounds__(256) void k_mlp1(const float* __restrict__ ea,
    const float* __restrict__ w1, const float* __restrict__ b1,
    const int* __restrict__ elist, unsigned short* __restrict__ hes) {
  int t = threadIdx.x, w = t >> 6, j = t & 63;
  int p0 = blockIdx.x * 32 + w * 8;
  float wr[16];
#pragma unroll
  for (int i = 0; i < 16; ++i) wr[i] = w1[j * 16 + i];
  float bj = b1[j];
#pragma unroll
  for (int q = 0; q < 8; ++q) {
    int p = p0 + q;
    int e = elist[p];
    const float* a = ea + (size_t)e * 16;
    float s = bj;
#pragma unroll
    for (int i = 0; i < 16; ++i) s += a[i] * wr[i];
    hes[(size_t)p * 64 + j] = f2bf(fmaxf(s, 0.f));
  }
}

// ---------------- CSR build by dst ----------------
__global__ __launch_bounds__(256) void k_hist(const int* __restrict__ eidx,
    int* __restrict__ cnt) {
  int e = blockIdx.x * 256 + threadIdx.x;
  atomicAdd(&cnt[eidx[N_E + e]], 1);
}

__global__ __launch_bounds__(1024) void k_scan(int* __restrict__ hist,
    int* __restrict__ starts) {
  __shared__ int part[1024];
  int t = threadIdx.x;
  const int CH = 20;
  int lo = t * CH;
  int hi = lo + CH; if (hi > N_N) hi = N_N;
  int s = 0;
  for (int i = lo; i < hi; ++i) s += hist[i];
  part[t] = s;
  __syncthreads();
  for (int off = 1; off < 1024; off <<= 1) {
    int v = (t >= off) ? part[t - off] : 0;
    __syncthreads();
    part[t] += v;
    __syncthreads();
  }
  int run = (t == 0) ? 0 : part[t - 1];
  for (int i = lo; i < hi; ++i) {
    int h = hist[i];
    starts[i] = run;
    hist[i] = run;          // cursor seed
    run += h;
  }
  if (t == 1023) starts[N_N] = part[1023];
}

__global__ __launch_bounds__(256) void k_scatter(const int* __restrict__ eidx,
    int* __restrict__ cur, int* __restrict__ elist, int* __restrict__ srcl) {
  int e = blockIdx.x * 256 + threadIdx.x;
  int dn = eidx[N_E + e];
  int pos = atomicAdd(&cur[dn], 1);
  elist[pos] = e;
  srcl[pos] = eidx[e];
}

// ---------------- pack B/B2 fragment layouts + zero cursor & pool ----------------
__global__ __launch_bounds__(256) void k_pack(const float* __restrict__ w2,
    const float* __restrict__ b2f, const float* __restrict__ rootw,
    const float* __restrict__ inw,
    unsigned short* __restrict__ Bp, unsigned short* __restrict__ B2p,
    int* __restrict__ cursor, float* __restrict__ pool) {
  int idx = blockIdx.x * 256 + threadIdx.x;
  const int GT = 580 * 256;
  if (idx < 135168) {
    int i = idx & 7, l = (idx >> 3) & 63, cbkb = idx >> 9;
    int cb = cbkb & 3, kb = cbkb >> 2;
    int r = kb * 32 + ((l >> 4) << 3) + i;
    int c = (cb << 4) + (l & 15);
    float v;
    if (r < 2048) { int d = r >> 6, k = r & 63; v = w2[((d << 6) + c) * 64 + k]; }
    else if (r < 2080) v = b2f[((r - 2048) << 6) + c];
    else v = rootw[((r - 2080) << 6) + c];
    Bp[idx] = f2bf(v);
  } else if (idx < 135168 + 12288) {
    int k2 = idx - 135168;
    int i = k2 & 7, l = (k2 >> 3) & 63, cbkb = k2 >> 9;
    int cb = cbkb % 12, kb = cbkb / 12;
    int r = kb * 32 + ((l >> 4) << 3) + i;
    int c = (cb << 4) + (l & 15);
    B2p[k2] = f2bf(inw[c * 64 + r]);
  }
  for (int i = idx; i < N_N; i += GT) cursor[i] = 0;
  for (int i = idx; i < 6400; i += GT) pool[i] = 0.f;
}

// ---------------- FUSED: LDS-DMA P-build + MFMA GEMM (M=8) + mean/bias/relu + QKV --------
// Block = 8 nodes, 512 threads = 8 waves, ONE wave per node. Per 8-edge chunk:
// 2x global_load_lds (he 1KB coalesced, x 1KB gathered) -> vmcnt(0) -> consume from LDS.
#define FMA8(hv, base, xv) \
  acc[base + 0] += xv * bflo(hv.x); acc[base + 1] += xv * bfhi(hv.x); \
  acc[base + 2] += xv * bflo(hv.y); acc[base + 3] += xv * bfhi(hv.y); \
  acc[base + 4] += xv * bflo(hv.z); acc[base + 5] += xv * bfhi(hv.z); \
  acc[base + 6] += xv * bflo(hv.w); acc[base + 7] += xv * bfhi(hv.w);

__global__ __launch_bounds__(512, 4) void k_fused(const float* __restrict__ x,
    const unsigned short* __restrict__ hes, const int* __restrict__ starts,
    const int* __restrict__ srcl,
    const unsigned short* __restrict__ Bp, const unsigned short* __restrict__ B2p,
    const float* __restrict__ convb, const float* __restrict__ inb,
    float* __restrict__ Qb, float* __restrict__ Kb, float* __restrict__ Vb) {
  __shared__ unsigned short Ps[8 * KA];                 // 33,792 B
  __shared__ __align__(16) unsigned short Hs[8 * 512];  //  8,192 B (8 waves x 1KB)
  __shared__ __align__(16) float Xs[8 * 256];           //  8,192 B
  __shared__ unsigned short xhT[8 * 68];                //  1,088 B
  int t = threadIdx.x, w = t >> 6, l = t & 63;
  int n0 = blockIdx.x * 8;
  int d0 = l >> 3, l31 = l & 31;
  unsigned short* Hw = Hs + w * 512;    // 8 rows x 64 shorts
  float* Xw = Xs + w * 256;             // 8 rows x 32 floats
  // ---- phase 1: wave w builds node n0+w via LDS-DMA chunks ----
  {
    int n = n0 + w;
    int s0 = starts[n], s1 = starts[n + 1];
    float acc[32];
#pragma unroll
    for (int z = 0; z < 32; ++z) acc[z] = 0.f;
    float xs = 0.f;
#pragma unroll 1
    for (int c0 = s0; c0 < s1; c0 += 64) {
      int srv = 0;
      if (c0 + l < s1) srv = srcl[c0 + l];
      int cc = s1 - c0; if (cc > 64) cc = 64;
#pragma unroll 1
      for (int j0 = 0; j0 < cc; j0 += 8) {
        int nedge = cc - j0; if (nedge > 8) nedge = 8;
        // stage he rows (coalesced): lane l -> row j0+(l>>3), 16B col (l&7)*16
        int slot = c0 + j0 + (l >> 3); if (slot >= s1) slot = s1 - 1;
        gload16(hes + (size_t)slot * 64 + (l & 7) * 8, Hw);
        // stage x rows (gathered): lane l -> row of edge j0+(l>>3)
        int sr = __shfl(srv, j0 + (l >> 3));
        gload16(x + (size_t)sr * 32 + (l & 7) * 4, Xw);
        asm volatile("s_waitcnt vmcnt(0)" ::: "memory");
#pragma unroll 1
        for (int i = 0; i < nedge; i += 2) {
          uint4 hA = *(const uint4*)(Hw + i * 64 + (l & 7) * 8);
          float a0 = Xw[i * 32 + d0],      a1 = Xw[i * 32 + d0 + 8];
          float a2 = Xw[i * 32 + d0 + 16], a3 = Xw[i * 32 + d0 + 24];
          float xsa = Xw[i * 32 + l31];
          uint4 hB = {0, 0, 0, 0};
          float b0 = 0.f, b1 = 0.f, b2 = 0.f, b3 = 0.f, xsb = 0.f;
          if (i + 1 < nedge) {
            hB = *(const uint4*)(Hw + (i + 1) * 64 + (l & 7) * 8);
            b0 = Xw[(i + 1) * 32 + d0];      b1 = Xw[(i + 1) * 32 + d0 + 8];
            b2 = Xw[(i + 1) * 32 + d0 + 16]; b3 = Xw[(i + 1) * 32 + d0 + 24];
            xsb = Xw[(i + 1) * 32 + l31];
          }
          FMA8(hA, 0, a0) FMA8(hA, 8, a1) FMA8(hA, 16, a2) FMA8(hA, 24, a3)
          FMA8(hB, 0, b0) FMA8(hB, 8, b1) FMA8(hB, 16, b2) FMA8(hB, 24, b3)
          xs += xsa + xsb;
        }
      }
    }
    int s = w;   // m = w in 0..7
#pragma unroll
    for (int q = 0; q < 4; ++q) {
      int scr = (l + 64 * q) ^ s;
      uint4 o;
      o.x = pk2(acc[q * 8 + 0], acc[q * 8 + 1]);
      o.y = pk2(acc[q * 8 + 2], acc[q * 8 + 3]);
      o.z = pk2(acc[q * 8 + 4], acc[q * 8 + 5]);
      o.w = pk2(acc[q * 8 + 6], acc[q * 8 + 7]);
      *(uint4*)(Ps + w * KA + scr * 8) = o;
    }
    if (l < 32) {
      int cnt = s1 - s0; if (cnt < 1) cnt = 1;
      int c1 = (256 + (l >> 3)) ^ s, c2 = (260 + (l >> 3)) ^ s;
      Ps[w * KA + c1 * 8 + (l & 7)] = f2bf(xs);
      Ps[w * KA + c2 * 8 + (l & 7)] = f2bf(x[(size_t)n * 32 + l] * (float)cnt);
    }
  }
  __syncthreads();
  // ---- phase 2: GEMM K-loop (M=8, rows duplicated), waves 0-3 own cols w*16..+16 ----
  int col = l & 15, sub = l >> 4;
  int arow = col & 7;
  if (w < 4) {
    const bfrag* Bb = (const bfrag*)Bp + w * 64 + l;
    facc ac = {0.f, 0.f, 0.f, 0.f};
#pragma unroll 4
    for (int kb = 0; kb < NKB; ++kb) {
      int scr = ((kb << 2) + sub) ^ arow;
      bfrag af = *(const bfrag*)(Ps + arow * KA + scr * 8);
      ac = __builtin_amdgcn_mfma_f32_16x16x32_bf16(af, Bb[kb * 256], ac, 0, 0, 0);
    }
    float cv = convb[w * 16 + col];
#pragma unroll
    for (int j = 0; j < 4; ++j) {
      int m = sub * 4 + j;
      if (m < 8) {
        int n = n0 + m;
        int cnt = starts[n + 1] - starts[n]; if (cnt < 1) cnt = 1;
        float inv = 1.f / (float)cnt;
        xhT[m * 68 + w * 16 + col] = f2bf(fmaxf(ac[j] * inv + cv, 0.f));
      }
    }
  }
  __syncthreads();
  // ---- phase 3: QKV (M=8), waves 0-3 own 3 of 12 col blocks ----
  if (w < 4) {
    bfrag af0 = *(const bfrag*)&xhT[(col & 7) * 68 + sub * 8];
    bfrag af1 = *(const bfrag*)&xhT[(col & 7) * 68 + 32 + sub * 8];
    const bfrag* B2b = (const bfrag*)B2p + l;
#pragma unroll
    for (int c3 = 0; c3 < 3; ++c3) {
      int cb = w * 3 + c3;
      facc qa = {0.f, 0.f, 0.f, 0.f};
      qa = __builtin_amdgcn_mfma_f32_16x16x32_bf16(af0, B2b[cb * 64], qa, 0, 0, 0);
      qa = __builtin_amdgcn_mfma_f32_16x16x32_bf16(af1, B2b[(12 + cb) * 64], qa, 0, 0, 0);
#pragma unroll
      for (int j = 0; j < 4; ++j) {
        int m = sub * 4 + j;
        if (m < 8) {
          int n = n0 + m;
          int g = n / 200, p = n - g * 200;
          int c = cb * 16 + col;
          float v = qa[j] + inb[c];
          int part = c >> 6, rem = c & 63, hh = rem >> 4, dd = rem & 15;
          float* dst = (part == 0) ? Qb : (part == 1 ? Kb : Vb);
          dst[(((size_t)g * 4 + hh) * 200 + p) * 16 + dd] = v;
        }
      }
    }
  }
}

// ---------------- MFMA flash attention + fused linear pooling ----------------
__global__ __launch_bounds__(256) void k_attn(const float* __restrict__ Qb,
    const float* __restrict__ Kb, const float* __restrict__ Vb,
    float* __restrict__ pool) {
  __shared__ unsigned short Ks[224 * 24];
  __shared__ unsigned short Vt[16 * 232];
  __shared__ unsigned short Pl[4][16 * 40];
  __shared__ float pw[4][16];
  int t = threadIdx.x;
  int gh = blockIdx.x >> 1, half = blockIdx.x & 1;
  size_t base = (size_t)gh * 3200;
  for (int idx = t; idx < 224 * 16; idx += 256) {
    int row = idx >> 4, d = idx & 15;
    float kv = (row < 200) ? Kb[base + idx] : 0.f;
    float vv = (row < 200) ? Vb[base + idx] : 0.f;
    Ks[row * 24 + d] = f2bf(kv);
    Vt[d * 232 + row] = f2bf(vv);
  }
  __syncthreads();
  int w = t >> 6, l = t & 63;
  int sub = l >> 4, col = l & 15;
  int qlo = half * 7, qhi = half ? 13 : 7;
  float pacc = 0.f;
  for (int qt = qlo + w; qt < qhi; qt += 4) {
    bfrag qf = {0, 0, 0, 0, 0, 0, 0, 0};
    int q = qt * 16 + col;
    if (sub < 2 && q < 200) {
      const float* qp = Qb + base + q * 16 + sub * 8;
      float4 qa = *(const float4*)qp;
      float4 qb = *(const float4*)(qp + 4);
      qf[0] = (short)f2bf(qa.x); qf[1] = (short)f2bf(qa.y);
      qf[2] = (short)f2bf(qa.z); qf[3] = (short)f2bf(qa.w);
      qf[4] = (short)f2bf(qb.x); qf[5] = (short)f2bf(qb.y);
      qf[6] = (short)f2bf(qb.z); qf[7] = (short)f2bf(qb.w);
    }
    facc o = {0.f, 0.f, 0.f, 0.f};
    float srow0 = 0.f, srow1 = 0.f, srow2 = 0.f, srow3 = 0.f;
    for (int kt2 = 0; kt2 < 7; ++kt2) {
      int kt0 = kt2 * 2, kt1 = kt0 + 1;
      bfrag kf0 = {0, 0, 0, 0, 0, 0, 0, 0};
      bfrag kf1 = {0, 0, 0, 0, 0, 0, 0, 0};
      if (sub < 2) {
        kf0 = *(const bfrag*)&Ks[(kt0 * 16 + col) * 24 + sub * 8];
        kf1 = *(const bfrag*)&Ks[(kt1 * 16 + col) * 24 + sub * 8];
      }
      facc z = {0.f, 0.f, 0.f, 0.f};
      facc s0 = __builtin_amdgcn_mfma_f32_16x16x32_bf16(qf, kf0, z, 0, 0, 0);
      facc s1 = __builtin_amdgcn_mfma_f32_16x16x32_bf16(qf, kf1, z, 0, 0, 0);
      bool ok0 = (kt0 * 16 + col) < 200;
      bool ok1 = (kt1 * 16 + col) < 200;
#pragma unroll
      for (int j = 0; j < 4; ++j) {
        float e0 = ok0 ? __expf(s0[j] * 0.25f) : 0.f;
        float e1 = ok1 ? __expf(s1[j] * 0.25f) : 0.f;
        if (j == 0) { srow0 += e0 + e1; } else if (j == 1) { srow1 += e0 + e1; }
        else if (j == 2) { srow2 += e0 + e1; } else { srow3 += e0 + e1; }
        int qr = (sub << 2) + j;
        Pl[w][qr * 40 + col] = f2bf(e0);
        Pl[w][qr * 40 + 16 + col] = f2bf(e1);
      }
      bfrag pf = *(const bfrag*)&Pl[w][col * 40 + sub * 8];
      bfrag vf = *(const bfrag*)&Vt[col * 232 + kt2 * 32 + sub * 8];
      o = __builtin_amdgcn_mfma_f32_16x16x32_bf16(pf, vf, o, 0, 0, 0);
    }
#pragma unroll
    for (int off = 1; off < 16; off <<= 1) {
      srow0 += __shfl_xor(srow0, off);
      srow1 += __shfl_xor(srow1, off);
      srow2 += __shfl_xor(srow2, off);
      srow3 += __shfl_xor(srow3, off);
    }
#pragma unroll
    for (int j = 0; j < 4; ++j) {
      int qq = qt * 16 + (sub << 2) + j;
      float sr = (j == 0) ? srow0 : (j == 1) ? srow1 : (j == 2) ? srow2 : srow3;
      if (qq < 200) pacc += o[j] / sr;
    }
  }
  pacc += __shfl_xor(pacc, 16);
  pacc += __shfl_xor(pacc, 32);
  if (l < 16) pw[w][l] = pacc;
  __syncthreads();
  if (t < 16) {
    float v = pw[0][t] + pw[1][t] + pw[2][t] + pw[3][t];
    atomicAdd(&pool[gh * 16 + t], v);
  }
}

// ---------------- head: out_proj(pool/200) + MLP ----------------
__global__ __launch_bounds__(64) void k_head(const float* __restrict__ pool,
    const float* __restrict__ ow, const float* __restrict__ ob,
    const float* __restrict__ w1, const float* __restrict__ b1,
    const float* __restrict__ w2, const float* __restrict__ b2,
    float* __restrict__ out) {
  __shared__ float ms[64], es[64];
  int g = blockIdx.x, t = threadIdx.x;
  ms[t] = pool[g * 64 + t] * (1.f / 200.f);
  __syncthreads();
  float e = ob[t];
  for (int j = 0; j < 64; ++j) e += ow[t * 64 + j] * ms[j];
  es[t] = e;
  __syncthreads();
  float h1 = b1[t];
  for (int j = 0; j < 64; ++j) h1 += w1[t * 64 + j] * es[j];
  h1 = fmaxf(h1, 0.f);
  float pr = h1 * w2[t];
  for (int off = 32; off >= 1; off >>= 1) pr += __shfl_xor(pr, off);
  if (t == 0) out[g] = pr + b2[0];
}

extern "C" void kernel_launch(void* const* d_in, const int* in_sizes, int n_in,
                              void* d_out, int out_size, void* d_ws, size_t ws_size,
                              hipStream_t stream) {
  (void)in_sizes; (void)n_in;
  const float* x      = (const float*)d_in[0];
  const int*   eidx   = (const int*)d_in[1];
  const float* ea     = (const float*)d_in[2];
  const float* en_w1  = (const float*)d_in[4];
  const float* en_b1  = (const float*)d_in[5];
  const float* en_w2  = (const float*)d_in[6];
  const float* en_b2  = (const float*)d_in[7];
  const float* root_w = (const float*)d_in[8];
  const float* conv_b = (const float*)d_in[9];
  const float* in_w   = (const float*)d_in[10];
  const float* in_b   = (const float*)d_in[11];
  const float* out_w  = (const float*)d_in[12];
  const float* out_b  = (const float*)d_in[13];
  const float* l1w    = (const float*)d_in[14];
  const float* l1b    = (const float*)d_in[15];
  const float* l2w    = (const float*)d_in[16];
  const float* l2b    = (const float*)d_in[17];
  float* out = (float*)d_out;

  // ---- workspace layout (bytes) ----
  char* w = (char*)d_ws;
  unsigned short* hes = (unsigned short*)w;            // 20,480,000 (dst-sorted he)
  float* Qb  = (float*)(w + 20480000);
  float* Kb  = (float*)(w + 25600000);
  float* Vb  = (float*)(w + 30720000);
  float* pool = (float*)(w + 35840000);                // 25,600 B
  char* r3 = w + 35870000;
  unsigned short* Bp  = (unsigned short*)r3;             // 270,336
  unsigned short* B2p = (unsigned short*)(r3 + 270336);  // 24,576
  int* starts = (int*)(r3 + 270336 + 24576);
  int* elist  = starts + (N_N + 4);
  int* srcl   = elist + N_E;
  int* cursor = srcl + N_E;
  size_t need = 35870000 + 270336 + 24576
              + (size_t)(N_N + 4) * 4 + 2 * (size_t)N_E * 4 + (size_t)N_N * 4;
  if (ws_size < need || out_size < 100) return;

  k_pack<<<580, 256, 0, stream>>>(en_w2, en_b2, root_w, in_w, Bp, B2p, cursor, pool);
  k_hist<<<N_E / 256, 256, 0, stream>>>(eidx, cursor);
  k_scan<<<1, 1024, 0, stream>>>(cursor, starts);
  k_scatter<<<N_E / 256, 256, 0, stream>>>(eidx, cursor, elist, srcl);
  k_mlp1<<<5000, 256, 0, stream>>>(ea, en_w1, en_b1, elist, hes);
  k_fused<<<2500, 512, 0, stream>>>(x, hes, starts, srcl, Bp, B2p,
                                    conv_b, in_b, Qb, Kb, Vb);
  k_attn<<<800, 256, 0, stream>>>(Qb, Kb, Vb, pool);
  k_head<<<100, 64, 0, stream>>>(pool, out_w, out_b, l1w, l1b, l2w, l2b, out);
}